// Round 10
// baseline (411.984 us; speedup 1.0000x reference)
//
#include <hip/hip_runtime.h>
#include <hip/hip_bf16.h>
#include <math.h>

#define D_DIM 2048
#define F_DIM 1408
#define FS_DIM 2816
#define E_NUM 8
#define N_TOK 2048

typedef __attribute__((ext_vector_type(8))) short bf16x8;
typedef __attribute__((ext_vector_type(4))) float f32x4;

#define WAITVM(n) asm volatile("s_waitcnt vmcnt(" #n ")" ::: "memory")

__device__ inline short f2bf(float f) {
    __hip_bfloat16 h = __float2bfloat16(f);
    return *reinterpret_cast<short*>(&h);
}
__device__ inline float bf2f(short s) {
    __hip_bfloat16 h; *reinterpret_cast<short*>(&h) = s;
    return __bfloat162float(h);
}
__device__ inline float silu1(float v) { return v / (1.f + expf(-v)); }

__device__ inline void async_copy16(const void* g, void* l) {
    __builtin_amdgcn_global_load_lds(
        (const __attribute__((address_space(1))) void*)g,
        (__attribute__((address_space(3))) void*)l, 16, 0, 0);
}

// 64x64 transpose+convert tile with explicit 256-thread id
__device__ inline void t64h(const float* in, short* out, int K, int N,
                            int kt, int nt, float (*tile)[65], int t)
{
    int k0 = kt * 64, n0 = nt * 64;
    int tr = t >> 4, tc4 = (t & 15) * 4;
#pragma unroll
    for (int i = 0; i < 4; ++i) {
        int r = tr + i * 16;
        float4 v = *reinterpret_cast<const float4*>(in + (size_t)(k0 + r) * N + n0 + tc4);
        tile[r][tc4 + 0] = v.x; tile[r][tc4 + 1] = v.y;
        tile[r][tc4 + 2] = v.z; tile[r][tc4 + 3] = v.w;
    }
    __syncthreads();
#pragma unroll
    for (int i = 0; i < 4; ++i) {
        int n = tr + i * 16;
        short4 s4;
        s4.x = f2bf(tile[tc4 + 0][n]);
        s4.y = f2bf(tile[tc4 + 1][n]);
        s4.z = f2bf(tile[tc4 + 2][n]);
        s4.w = f2bf(tile[tc4 + 3][n]);
        *reinterpret_cast<short4*>(out + (size_t)(n0 + n) * K + k0 + tc4) = s4;
    }
}

// ---------------- prep: gate | cvt_x | transpose(sw1,sw3,rw1,rw3) ----------------
__global__ __launch_bounds__(256) void prep_kernel(
    const float* __restrict__ x, const float* __restrict__ gw,
    float* __restrict__ assign_w, int* __restrict__ expert_count,
    int* __restrict__ expert_list, short* __restrict__ Xb,
    const float* __restrict__ sw1, short* __restrict__ swt1,
    const float* __restrict__ sw3, short* __restrict__ swt3,
    const float* __restrict__ rw1, short* __restrict__ rwt1,
    const float* __restrict__ rw3, short* __restrict__ rwt3)
{
    __shared__ float tile[64][65];
    int bid = blockIdx.x;
    int tid = threadIdx.x;
    if (bid < 512) {
        int wid = bid * 4 + (tid >> 6);
        int lane = tid & 63;
        const float* xr = x + (size_t)wid * D_DIM;
        float p[E_NUM];
#pragma unroll
        for (int e = 0; e < E_NUM; ++e) p[e] = 0.f;
        for (int d = lane; d < D_DIM; d += 64) {
            float xv = xr[d];
            const float4* g = reinterpret_cast<const float4*>(gw + (size_t)d * E_NUM);
            float4 g0 = g[0], g1 = g[1];
            p[0] = fmaf(xv, g0.x, p[0]); p[1] = fmaf(xv, g0.y, p[1]);
            p[2] = fmaf(xv, g0.z, p[2]); p[3] = fmaf(xv, g0.w, p[3]);
            p[4] = fmaf(xv, g1.x, p[4]); p[5] = fmaf(xv, g1.y, p[5]);
            p[6] = fmaf(xv, g1.z, p[6]); p[7] = fmaf(xv, g1.w, p[7]);
        }
#pragma unroll
        for (int off = 32; off > 0; off >>= 1)
#pragma unroll
            for (int e = 0; e < E_NUM; ++e)
                p[e] += __shfl_xor(p[e], off, 64);
        if (lane == 0) {
            float m = p[0];
#pragma unroll
            for (int e = 1; e < E_NUM; ++e) m = fmaxf(m, p[e]);
            float s = 0.f, pr[E_NUM];
#pragma unroll
            for (int e = 0; e < E_NUM; ++e) { pr[e] = expf(p[e] - m); s += pr[e]; }
            float inv = 1.f / s;
#pragma unroll
            for (int e = 0; e < E_NUM; ++e) pr[e] *= inv;
            int i0 = 0;
#pragma unroll
            for (int e = 1; e < E_NUM; ++e) if (pr[e] > pr[i0]) i0 = e;
            int i1 = (i0 == 0) ? 1 : 0;
#pragma unroll
            for (int e = 0; e < E_NUM; ++e) if (e != i0 && pr[e] > pr[i1]) i1 = e;
            int s0 = wid * 2, s1 = wid * 2 + 1;
            assign_w[s0] = pr[i0];
            assign_w[s1] = pr[i1];
            int p0 = atomicAdd(&expert_count[i0], 1);
            expert_list[i0 * N_TOK + p0] = s0;
            int p1 = atomicAdd(&expert_count[i1], 1);
            expert_list[i1 * N_TOK + p1] = s1;
        }
    } else if (bid < 2560) {
        int i = ((bid - 512) * 256 + tid) * 8;
        float4 v0 = *reinterpret_cast<const float4*>(x + i);
        float4 v1 = *reinterpret_cast<const float4*>(x + i + 4);
        bf16x8 o;
        o[0] = f2bf(v0.x); o[1] = f2bf(v0.y); o[2] = f2bf(v0.z); o[3] = f2bf(v0.w);
        o[4] = f2bf(v1.x); o[5] = f2bf(v1.y); o[6] = f2bf(v1.z); o[7] = f2bf(v1.w);
        *reinterpret_cast<bf16x8*>(Xb + i) = o;
    } else if (bid < 3968) {
        int t = bid - 2560;
        t64h(sw1, swt1, D_DIM, FS_DIM, t % 32, t / 32, tile, tid);
    } else if (bid < 5376) {
        int t = bid - 3968;
        t64h(sw3, swt3, D_DIM, FS_DIM, t % 32, t / 32, tile, tid);
    } else if (bid < 11008) {
        int t = bid - 5376;
        int e = t / 704, r = t % 704;
        t64h(rw1 + (size_t)e * D_DIM * F_DIM, rwt1 + (size_t)e * F_DIM * D_DIM,
             D_DIM, F_DIM, r % 32, r / 32, tile, tid);
    } else {
        int t = bid - 11008;
        int e = t / 704, r = t % 704;
        t64h(rw3 + (size_t)e * D_DIM * F_DIM, rwt3 + (size_t)e * F_DIM * D_DIM,
             D_DIM, F_DIM, r % 32, r / 32, tile, tid);
    }
}

// ---------------- in-GEMM: BM=256 BN=128(each B) BK=32, 512 thr, 4-buf depth-3 ----
// Per buf (32KB): A 256x64B (16K) | B1 128x64B (8K) | B3 (8K). 8 waves 2m x 4n.
// Correct order per iter: WAITVM(8) -> s_barrier -> frag reads (all waves' loads
// for tile t are complete). Counted vmcnt never 0 in loop.
__global__ __launch_bounds__(512) void moe_in_kernel(
    const short* __restrict__ Xb,
    const short* __restrict__ swt1, const short* __restrict__ swt3, short* __restrict__ Hs,
    const short* __restrict__ rwt1, const short* __restrict__ rwt3, short* __restrict__ Hr,
    const int* __restrict__ expert_list, const int* __restrict__ expert_count,
    const float* __restrict__ sw2, short* __restrict__ swt2,
    const float* __restrict__ rw2, short* __restrict__ rwt2)
{
    __shared__ char SMEM[131072];
    int bid = blockIdx.x, tid = threadIdx.x;

    if (bid >= 896) {
        int t2 = (bid - 896) * 2 + (tid >> 8);
        int t256 = tid & 255;
        float (*tile)[65] = reinterpret_cast<float (*)[65]>(SMEM + (tid >> 8) * 16640);
        if (t2 < 1408) {
            t64h(sw2, swt2, FS_DIM, D_DIM, t2 % 44, t2 / 44, tile, t256);
        } else {
            int r = t2 - 1408;
            int e = r / 704, rr = r % 704;
            t64h(rw2 + (size_t)e * F_DIM * D_DIM, rwt2 + (size_t)e * D_DIM * F_DIM,
                 F_DIM, D_DIM, rr % 22, rr / 22, tile, t256);
        }
        return;
    }

    int xcd = bid & 7, qq = bid >> 3, mtile = qq & 7, gq = qq >> 3;
    int g = gq * 8 + xcd;
    if (g >= 110) return;
    bool gather;
    const short *W1, *W3;
    short* H;
    int ldH, n0, count;
    const int* list = nullptr;
    int m0 = mtile * 256;
    if (g < 22) {
        gather = false; count = N_TOK;
        W1 = swt1; W3 = swt3; H = Hs; ldH = FS_DIM; n0 = g * 128;
    } else {
        int g2 = g - 22, e = g2 / 11;
        n0 = (g2 % 11) * 128;
        gather = true;
        count = expert_count[e];
        if (m0 >= count) return;
        list = expert_list + e * N_TOK;
        W1 = rwt1 + (size_t)e * F_DIM * D_DIM;
        W3 = rwt3 + (size_t)e * F_DIM * D_DIM;
        H = Hr; ldH = F_DIM;
    }

    int l = tid & 63, w = tid >> 6;
    int wm = w >> 2, wn = w & 3, frow = l & 15, fkg = l >> 4;

    // staging source pointers (pre-swizzled: 16B slot s of row r at s^(r&3))
    const char* aS[2];
#pragma unroll
    for (int j = 0; j < 2; ++j) {
        int u = j * 512 + tid, r = u >> 2, s = u & 3;
        int rr = m0 + r;
        int tok = gather ? ((rr < count) ? (list[rr] >> 1) : 0) : rr;
        aS[j] = (const char*)Xb + (size_t)tok * 4096 + ((s ^ (r & 3)) << 4);
    }
    int brr = tid >> 2, bss = tid & 3;
    size_t boff = (size_t)(n0 + brr) * 4096 + ((bss ^ (brr & 3)) << 4);
    const char* b1S = (const char*)W1 + boff;
    const char* b3S = (const char*)W3 + boff;

    f32x4 acc1[8][2], acc3[8][2];
#pragma unroll
    for (int i = 0; i < 8; ++i)
#pragma unroll
        for (int j = 0; j < 2; ++j) { acc1[i][j] = (f32x4)0.f; acc3[i][j] = (f32x4)0.f; }

    // prologue: stage K-tiles 0,1,2 (4 loads each per wave -> 12 outstanding)
#pragma unroll
    for (int p = 0; p < 3; ++p) {
        char* base = SMEM + p * 32768;
        int kb = p << 6;
        async_copy16(aS[0] + kb, base + tid * 16);
        async_copy16(aS[1] + kb, base + (512 + tid) * 16);
        async_copy16(b1S + kb, base + 16384 + tid * 16);
        async_copy16(b3S + kb, base + 24576 + tid * 16);
    }

    for (int t = 0; t < 64; ++t) {
        const char* base = SMEM + (t & 3) * 32768;
        int ts = (t + 3 < 64) ? (t + 3) : 63;
        char* sbase = SMEM + ((t + 3) & 3) * 32768;
        int skb = ts << 6;
        WAITVM(8);                        // own tile-t loads complete
        __builtin_amdgcn_s_barrier();     // ALL waves' tile-t loads complete
        // ---- phase 0: A+B1 frags, stage next A, MFMA acc1 ----
        bf16x8 af[8], bf[2];
#pragma unroll
        for (int mf = 0; mf < 8; ++mf) {
            int r = wm * 128 + mf * 16 + frow;
            af[mf] = *reinterpret_cast<const bf16x8*>(
                base + r * 64 + ((fkg ^ (r & 3)) << 4));
        }
#pragma unroll
        for (int nf = 0; nf < 2; ++nf) {
            int rb = wn * 32 + nf * 16 + frow;
            bf[nf] = *reinterpret_cast<const bf16x8*>(
                base + 16384 + rb * 64 + ((fkg ^ (rb & 3)) << 4));
        }
        async_copy16(aS[0] + skb, sbase + tid * 16);
        async_copy16(aS[1] + skb, sbase + (512 + tid) * 16);
        __builtin_amdgcn_s_setprio(1);
#pragma unroll
        for (int mf = 0; mf < 8; ++mf)
#pragma unroll
            for (int nf = 0; nf < 2; ++nf)
                acc1[mf][nf] = __builtin_amdgcn_mfma_f32_16x16x32_bf16(
                    af[mf], bf[nf], acc1[mf][nf], 0, 0, 0);
        __builtin_amdgcn_s_setprio(0);
        __builtin_amdgcn_s_barrier();
        // ---- phase 1: B3 frags, stage next B, MFMA acc3 ----
#pragma unroll
        for (int nf = 0; nf < 2; ++nf) {
            int rb = wn * 32 + nf * 16 + frow;
            bf[nf] = *reinterpret_cast<const bf16x8*>(
                base + 24576 + rb * 64 + ((fkg ^ (rb & 3)) << 4));
        }
        async_copy16(b1S + skb, sbase + 16384 + tid * 16);
        async_copy16(b3S + skb, sbase + 24576 + tid * 16);
        __builtin_amdgcn_s_setprio(1);
#pragma unroll
        for (int mf = 0; mf < 8; ++mf)
#pragma unroll
            for (int nf = 0; nf < 2; ++nf)
                acc3[mf][nf] = __builtin_amdgcn_mfma_f32_16x16x32_bf16(
                    af[mf], bf[nf], acc3[mf][nf], 0, 0, 0);
        __builtin_amdgcn_s_setprio(0);
    }
    WAITVM(0);

#pragma unroll
    for (int mf = 0; mf < 8; ++mf) {
#pragma unroll
        for (int jj = 0; jj < 4; ++jj) {
            int rl = wm * 128 + mf * 16 + fkg * 4 + jj;
            int rr = m0 + rl;
            int s;
            if (gather) { if (rr >= count) continue; s = list[rr]; }
            else s = rr;
            short* hp = H + (size_t)s * ldH + n0 + wn * 32 + frow;
#pragma unroll
            for (int nf = 0; nf < 2; ++nf)
                hp[nf * 16] = f2bf(silu1(acc1[mf][nf][jj]) * acc3[mf][nf][jj]);
        }
    }
}

// ---------------- out-GEMM: BM=256 BN=128 BK=32, 512 thr, 4-buf depth-3 ----------
// Per buf (24KB): A 256x64B (16K) | B 128x64B (8K). Counted vmcnt(6).
__global__ __launch_bounds__(512) void moe_out_kernel(
    const short* __restrict__ Hs, const short* __restrict__ swt2, float* __restrict__ Y,
    const short* __restrict__ Hr, const short* __restrict__ rwt2, short* __restrict__ H2,
    const int* __restrict__ expert_list, const int* __restrict__ expert_count)
{
    __shared__ char SMEM[98304];
    int bid = blockIdx.x, tid = threadIdx.x;
    int xcd = bid & 7, qq = bid >> 3, mtile = qq & 7, gq = qq >> 3;
    int g = gq * 8 + xcd;
    if (g >= 144) return;
    bool gather;
    const short *A, *B;
    int ldKb, NIT, n0, count;
    const int* list = nullptr;
    int m0 = mtile * 256;
    if (g < 16) {
        gather = false; count = N_TOK;
        A = Hs; ldKb = FS_DIM * 2; NIT = 88; B = swt2; n0 = g * 128;
    } else {
        int g2 = g - 16, e = g2 >> 4;
        n0 = (g2 & 15) * 128;
        gather = true;
        count = expert_count[e];
        if (m0 >= count) return;
        list = expert_list + e * N_TOK;
        A = Hr; ldKb = F_DIM * 2; NIT = 44;
        B = rwt2 + (size_t)e * D_DIM * F_DIM;
    }

    int l = tid & 63, w = tid >> 6;
    int wm = w >> 2, wn = w & 3, frow = l & 15, fkg = l >> 4;

    const char* aS[2];
#pragma unroll
    for (int j = 0; j < 2; ++j) {
        int u = j * 512 + tid, r = u >> 2, s = u & 3;
        int rr = m0 + r;
        int arow = gather ? ((rr < count) ? list[rr] : 0) : rr;
        aS[j] = (const char*)A + (size_t)arow * ldKb + ((s ^ (r & 3)) << 4);
    }
    int brr = tid >> 2, bss = tid & 3;
    const char* bS = (const char*)B + (size_t)(n0 + brr) * ldKb + ((bss ^ (brr & 3)) << 4);

    f32x4 acc[8][2];
#pragma unroll
    for (int i = 0; i < 8; ++i)
#pragma unroll
        for (int j = 0; j < 2; ++j) acc[i][j] = (f32x4)0.f;

#pragma unroll
    for (int p = 0; p < 3; ++p) {
        char* base = SMEM + p * 24576;
        int kb = p << 6;
        async_copy16(aS[0] + kb, base + tid * 16);
        async_copy16(aS[1] + kb, base + (512 + tid) * 16);
        async_copy16(bS + kb, base + 16384 + tid * 16);
    }

    for (int t = 0; t < NIT; ++t) {
        const char* base = SMEM + (t & 3) * 24576;
        int ts = (t + 3 < NIT) ? (t + 3) : (NIT - 1);
        char* sbase = SMEM + ((t + 3) & 3) * 24576;
        int skb = ts << 6;
        WAITVM(6);
        __builtin_amdgcn_s_barrier();     // all waves' tile-t loads complete
        // ---- phase 0: A frags + B frag 0, stage next A, 8 MFMA ----
        bf16x8 af[8], bf0, bf1;
#pragma unroll
        for (int mf = 0; mf < 8; ++mf) {
            int r = wm * 128 + mf * 16 + frow;
            af[mf] = *reinterpret_cast<const bf16x8*>(
                base + r * 64 + ((fkg ^ (r & 3)) << 4));
        }
        {
            int rb = wn * 32 + frow;
            bf0 = *reinterpret_cast<const bf16x8*>(
                base + 16384 + rb * 64 + ((fkg ^ (rb & 3)) << 4));
        }
        async_copy16(aS[0] + skb, sbase + tid * 16);
        async_copy16(aS[1] + skb, sbase + (512 + tid) * 16);
        __builtin_amdgcn_s_setprio(1);
#pragma unroll
        for (int mf = 0; mf < 8; ++mf)
            acc[mf][0] = __builtin_amdgcn_mfma_f32_16x16x32_bf16(
                af[mf], bf0, acc[mf][0], 0, 0, 0);
        __builtin_amdgcn_s_setprio(0);
        __builtin_amdgcn_s_barrier();
        // ---- phase 1: B frag 1, stage next B, 8 MFMA ----
        {
            int rb = wn * 32 + 16 + frow;
            bf1 = *reinterpret_cast<const bf16x8*>(
                base + 16384 + rb * 64 + ((fkg ^ (rb & 3)) << 4));
        }
        async_copy16(bS + skb, sbase + 16384 + tid * 16);
        __builtin_amdgcn_s_setprio(1);
#pragma unroll
        for (int mf = 0; mf < 8; ++mf)
            acc[mf][1] = __builtin_amdgcn_mfma_f32_16x16x32_bf16(
                af[mf], bf1, acc[mf][1], 0, 0, 0);
        __builtin_amdgcn_s_setprio(0);
    }
    WAITVM(0);

#pragma unroll
    for (int mf = 0; mf < 8; ++mf) {
#pragma unroll
        for (int jj = 0; jj < 4; ++jj) {
            int rl = wm * 128 + mf * 16 + fkg * 4 + jj;
            int rr = m0 + rl;
            int s;
            if (gather) { if (rr >= count) continue; s = list[rr]; }
            else s = rr;
            int col = n0 + wn * 32 + frow;
            if (!gather) {
                float* op = Y + (size_t)s * D_DIM + col;
                op[0] = acc[mf][0][jj];
                op[16] = acc[mf][1][jj];
            } else {
                short* op = H2 + (size_t)s * D_DIM + col;
                op[0] = f2bf(acc[mf][0][jj]);
                op[16] = f2bf(acc[mf][1][jj]);
            }
        }
    }
}

// ---------------- combine (H2 bf16) ----------------
__global__ __launch_bounds__(256) void combine_kernel(
    float* __restrict__ Y, const short* __restrict__ H2,
    const float* __restrict__ assign_w)
{
    int tok = blockIdx.x, tid = threadIdx.x;
    float w0 = assign_w[2 * tok];
    float w1 = assign_w[2 * tok + 1];
    const short* h0 = H2 + (size_t)(2 * tok) * D_DIM + tid * 8;
    const short* h1 = h0 + D_DIM;
    bf16x8 a = *reinterpret_cast<const bf16x8*>(h0);
    bf16x8 b = *reinterpret_cast<const bf16x8*>(h1);
    float* y = Y + (size_t)tok * D_DIM + tid * 8;
    float4 y0 = *reinterpret_cast<float4*>(y);
    float4 y1 = *reinterpret_cast<float4*>(y + 4);
    y0.x = fmaf(w0, bf2f(a[0]), fmaf(w1, bf2f(b[0]), y0.x));
    y0.y = fmaf(w0, bf2f(a[1]), fmaf(w1, bf2f(b[1]), y0.y));
    y0.z = fmaf(w0, bf2f(a[2]), fmaf(w1, bf2f(b[2]), y0.z));
    y0.w = fmaf(w0, bf2f(a[3]), fmaf(w1, bf2f(b[3]), y0.w));
    y1.x = fmaf(w0, bf2f(a[4]), fmaf(w1, bf2f(b[4]), y1.x));
    y1.y = fmaf(w0, bf2f(a[5]), fmaf(w1, bf2f(b[5]), y1.y));
    y1.z = fmaf(w0, bf2f(a[6]), fmaf(w1, bf2f(b[6]), y1.z));
    y1.w = fmaf(w0, bf2f(a[7]), fmaf(w1, bf2f(b[7]), y1.w));
    *reinterpret_cast<float4*>(y) = y0;
    *reinterpret_cast<float4*>(y + 4) = y1;
}

extern "C" void kernel_launch(void* const* d_in, const int* in_sizes, int n_in,
                              void* d_out, int out_size, void* d_ws, size_t ws_size,
                              hipStream_t stream) {
    const float* x   = (const float*)d_in[0];
    const float* gw  = (const float*)d_in[1];
    const float* sw1 = (const float*)d_in[2];
    const float* sw2 = (const float*)d_in[3];
    const float* sw3 = (const float*)d_in[4];
    const float* rw1 = (const float*)d_in[5];
    const float* rw2 = (const float*)d_in[6];
    const float* rw3 = (const float*)d_in[7];
    float* Y = (float*)d_out;

    char* ws = (char*)d_ws;
    float* assign_w     = (float*)(ws);
    int*   expert_count = (int*)(ws + 16384);
    int*   expert_list  = (int*)(ws + 16384 + 256);

    const size_t XB_OFF   = 131072;
    const size_t SWT1_OFF = XB_OFF + 8388608ull;
    const size_t SWT3_OFF = SWT1_OFF + 11534336ull;
    const size_t SWT2_OFF = SWT3_OFF + 11534336ull;
    const size_t RWT1_OFF = SWT2_OFF + 11534336ull;
    const size_t RWT3_OFF = RWT1_OFF + 46137344ull;
    const size_t RWT2_OFF = RWT3_OFF + 46137344ull;
    const size_t HS_OFF   = RWT2_OFF + 46137344ull;
    const size_t HR_OFF   = HS_OFF + 11534336ull;
    const size_t H2_OFF   = HR_OFF + 11534336ull;

    short* Xb   = (short*)(ws + XB_OFF);
    short* swt1 = (short*)(ws + SWT1_OFF);
    short* swt3 = (short*)(ws + SWT3_OFF);
    short* swt2 = (short*)(ws + SWT2_OFF);
    short* rwt1 = (short*)(ws + RWT1_OFF);
    short* rwt3 = (short*)(ws + RWT3_OFF);
    short* rwt2 = (short*)(ws + RWT2_OFF);
    short* Hs   = (short*)(ws + HS_OFF);
    short* Hr   = (short*)(ws + HR_OFF);
    short* H2   = (short*)(ws + H2_OFF);

    hipMemsetAsync(expert_count, 0, E_NUM * sizeof(int), stream);

    prep_kernel<<<16640, 256, 0, stream>>>(
        x, gw, assign_w, expert_count, expert_list, Xb,
        sw1, swt1, sw3, swt3, rw1, rwt1, rw3, rwt3);

    // 110 groups (22 shared-in + 88 routed-in) x 8 mtiles, XCD-mapped -> 896
    // + 3520 transpose blocks (7040 tiles, 2 per block)
    moe_in_kernel<<<4416, 512, 0, stream>>>(
        Xb, swt1, swt3, Hs, rwt1, rwt3, Hr,
        expert_list, expert_count, sw2, swt2, rw2, rwt2);

    // 144 groups (16 shared-out + 128 routed-out) x 8 mtiles -> 1152
    moe_out_kernel<<<1152, 512, 0, stream>>>(
        Hs, swt2, Y, Hr, rwt2, H2, expert_list, expert_count);

    combine_kernel<<<N_TOK, 256, 0, stream>>>(Y, H2, assign_w);
}

// Round 11
// 381.470 us; speedup vs baseline: 1.0800x; 1.0800x over previous
//
#include <hip/hip_runtime.h>
#include <hip/hip_bf16.h>
#include <math.h>

#define D_DIM 2048
#define F_DIM 1408
#define FS_DIM 2816
#define E_NUM 8
#define N_TOK 2048

typedef __attribute__((ext_vector_type(8))) short bf16x8;
typedef __attribute__((ext_vector_type(4))) float f32x4;

#define WAITVM(n) asm volatile("s_waitcnt vmcnt(" #n ")" ::: "memory")

__device__ inline short f2bf(float f) {
    __hip_bfloat16 h = __float2bfloat16(f);
    return *reinterpret_cast<short*>(&h);
}
__device__ inline float bf2f(short s) {
    __hip_bfloat16 h; *reinterpret_cast<short*>(&h) = s;
    return __bfloat162float(h);
}
__device__ inline float silu1(float v) { return v / (1.f + expf(-v)); }

__device__ inline void async_copy16(const void* g, void* l) {
    __builtin_amdgcn_global_load_lds(
        (const __attribute__((address_space(1))) void*)g,
        (__attribute__((address_space(3))) void*)l, 16, 0, 0);
}

// swizzle for 64B LDS rows: 16B slot s of row r stored at s ^ ((r>>1)&3)
#define SWZ(r, s) (((s) ^ (((r) >> 1) & 3)) << 4)

// 64x64 transpose+convert tile with explicit 256-thread id
__device__ inline void t64h(const float* in, short* out, int K, int N,
                            int kt, int nt, float (*tile)[65], int t)
{
    int k0 = kt * 64, n0 = nt * 64;
    int tr = t >> 4, tc4 = (t & 15) * 4;
#pragma unroll
    for (int i = 0; i < 4; ++i) {
        int r = tr + i * 16;
        float4 v = *reinterpret_cast<const float4*>(in + (size_t)(k0 + r) * N + n0 + tc4);
        tile[r][tc4 + 0] = v.x; tile[r][tc4 + 1] = v.y;
        tile[r][tc4 + 2] = v.z; tile[r][tc4 + 3] = v.w;
    }
    __syncthreads();
#pragma unroll
    for (int i = 0; i < 4; ++i) {
        int n = tr + i * 16;
        short4 s4;
        s4.x = f2bf(tile[tc4 + 0][n]);
        s4.y = f2bf(tile[tc4 + 1][n]);
        s4.z = f2bf(tile[tc4 + 2][n]);
        s4.w = f2bf(tile[tc4 + 3][n]);
        *reinterpret_cast<short4*>(out + (size_t)(n0 + n) * K + k0 + tc4) = s4;
    }
}

// ---------------- prep: gate | cvt_x | transpose(sw1,sw3,rw1,rw3) ----------------
__global__ __launch_bounds__(256) void prep_kernel(
    const float* __restrict__ x, const float* __restrict__ gw,
    float* __restrict__ assign_w, int* __restrict__ expert_count,
    int* __restrict__ expert_list, short* __restrict__ Xb,
    const float* __restrict__ sw1, short* __restrict__ swt1,
    const float* __restrict__ sw3, short* __restrict__ swt3,
    const float* __restrict__ rw1, short* __restrict__ rwt1,
    const float* __restrict__ rw3, short* __restrict__ rwt3)
{
    __shared__ float tile[64][65];
    int bid = blockIdx.x;
    int tid = threadIdx.x;
    if (bid < 512) {
        int wid = bid * 4 + (tid >> 6);
        int lane = tid & 63;
        const float* xr = x + (size_t)wid * D_DIM;
        float p[E_NUM];
#pragma unroll
        for (int e = 0; e < E_NUM; ++e) p[e] = 0.f;
        for (int d = lane; d < D_DIM; d += 64) {
            float xv = xr[d];
            const float4* g = reinterpret_cast<const float4*>(gw + (size_t)d * E_NUM);
            float4 g0 = g[0], g1 = g[1];
            p[0] = fmaf(xv, g0.x, p[0]); p[1] = fmaf(xv, g0.y, p[1]);
            p[2] = fmaf(xv, g0.z, p[2]); p[3] = fmaf(xv, g0.w, p[3]);
            p[4] = fmaf(xv, g1.x, p[4]); p[5] = fmaf(xv, g1.y, p[5]);
            p[6] = fmaf(xv, g1.z, p[6]); p[7] = fmaf(xv, g1.w, p[7]);
        }
#pragma unroll
        for (int off = 32; off > 0; off >>= 1)
#pragma unroll
            for (int e = 0; e < E_NUM; ++e)
                p[e] += __shfl_xor(p[e], off, 64);
        if (lane == 0) {
            float m = p[0];
#pragma unroll
            for (int e = 1; e < E_NUM; ++e) m = fmaxf(m, p[e]);
            float s = 0.f, pr[E_NUM];
#pragma unroll
            for (int e = 0; e < E_NUM; ++e) { pr[e] = expf(p[e] - m); s += pr[e]; }
            float inv = 1.f / s;
#pragma unroll
            for (int e = 0; e < E_NUM; ++e) pr[e] *= inv;
            int i0 = 0;
#pragma unroll
            for (int e = 1; e < E_NUM; ++e) if (pr[e] > pr[i0]) i0 = e;
            int i1 = (i0 == 0) ? 1 : 0;
#pragma unroll
            for (int e = 0; e < E_NUM; ++e) if (e != i0 && pr[e] > pr[i1]) i1 = e;
            int s0 = wid * 2, s1 = wid * 2 + 1;
            assign_w[s0] = pr[i0];
            assign_w[s1] = pr[i1];
            int p0 = atomicAdd(&expert_count[i0], 1);
            expert_list[i0 * N_TOK + p0] = s0;
            int p1 = atomicAdd(&expert_count[i1], 1);
            expert_list[i1 * N_TOK + p1] = s1;
        }
    } else if (bid < 2560) {
        int i = ((bid - 512) * 256 + tid) * 8;
        float4 v0 = *reinterpret_cast<const float4*>(x + i);
        float4 v1 = *reinterpret_cast<const float4*>(x + i + 4);
        bf16x8 o;
        o[0] = f2bf(v0.x); o[1] = f2bf(v0.y); o[2] = f2bf(v0.z); o[3] = f2bf(v0.w);
        o[4] = f2bf(v1.x); o[5] = f2bf(v1.y); o[6] = f2bf(v1.z); o[7] = f2bf(v1.w);
        *reinterpret_cast<bf16x8*>(Xb + i) = o;
    } else if (bid < 3968) {
        int t = bid - 2560;
        t64h(sw1, swt1, D_DIM, FS_DIM, t % 32, t / 32, tile, tid);
    } else if (bid < 5376) {
        int t = bid - 3968;
        t64h(sw3, swt3, D_DIM, FS_DIM, t % 32, t / 32, tile, tid);
    } else if (bid < 11008) {
        int t = bid - 5376;
        int e = t / 704, r = t % 704;
        t64h(rw1 + (size_t)e * D_DIM * F_DIM, rwt1 + (size_t)e * F_DIM * D_DIM,
             D_DIM, F_DIM, r % 32, r / 32, tile, tid);
    } else {
        int t = bid - 11008;
        int e = t / 704, r = t % 704;
        t64h(rw3 + (size_t)e * D_DIM * F_DIM, rwt3 + (size_t)e * F_DIM * D_DIM,
             D_DIM, F_DIM, r % 32, r / 32, tile, tid);
    }
}

// ---------------- in-GEMM: BM=256 BN=128(each B) BK=32, 512 thr, 4-buf depth-3 ----
// Per buf (32KB): A 256x64B (16K) | B1 128x64B (8K) | B3 (8K). 8 waves 2m x 4n.
// Order per iter: WAITVM(8) -> s_barrier -> frag reads. Swizzle f(r)=(r>>1)&3.
__global__ __launch_bounds__(512) void moe_in_kernel(
    const short* __restrict__ Xb,
    const short* __restrict__ swt1, const short* __restrict__ swt3, short* __restrict__ Hs,
    const short* __restrict__ rwt1, const short* __restrict__ rwt3, short* __restrict__ Hr,
    const int* __restrict__ expert_list, const int* __restrict__ expert_count,
    const float* __restrict__ sw2, short* __restrict__ swt2,
    const float* __restrict__ rw2, short* __restrict__ rwt2)
{
    __shared__ char SMEM[131072];
    int bid = blockIdx.x, tid = threadIdx.x;

    if (bid >= 896) {
        int t2 = (bid - 896) * 2 + (tid >> 8);
        int t256 = tid & 255;
        float (*tile)[65] = reinterpret_cast<float (*)[65]>(SMEM + (tid >> 8) * 16640);
        if (t2 < 1408) {
            t64h(sw2, swt2, FS_DIM, D_DIM, t2 % 44, t2 / 44, tile, t256);
        } else {
            int r = t2 - 1408;
            int e = r / 704, rr = r % 704;
            t64h(rw2 + (size_t)e * F_DIM * D_DIM, rwt2 + (size_t)e * D_DIM * F_DIM,
                 F_DIM, D_DIM, rr % 22, rr / 22, tile, t256);
        }
        return;
    }

    int xcd = bid & 7, qq = bid >> 3, mtile = qq & 7, gq = qq >> 3;
    int g = gq * 8 + xcd;
    if (g >= 110) return;
    bool gather;
    const short *W1, *W3;
    short* H;
    int ldH, n0, count;
    const int* list = nullptr;
    int m0 = mtile * 256;
    if (g < 22) {
        gather = false; count = N_TOK;
        W1 = swt1; W3 = swt3; H = Hs; ldH = FS_DIM; n0 = g * 128;
    } else {
        int g2 = g - 22, e = g2 / 11;
        n0 = (g2 % 11) * 128;
        gather = true;
        count = expert_count[e];
        if (m0 >= count) return;
        list = expert_list + e * N_TOK;
        W1 = rwt1 + (size_t)e * F_DIM * D_DIM;
        W3 = rwt3 + (size_t)e * F_DIM * D_DIM;
        H = Hr; ldH = F_DIM;
    }

    int l = tid & 63, w = tid >> 6;
    int wm = w >> 2, wn = w & 3, frow = l & 15, fkg = l >> 4;

    const char* aS[2];
#pragma unroll
    for (int j = 0; j < 2; ++j) {
        int u = j * 512 + tid, r = u >> 2, s = u & 3;
        int rr = m0 + r;
        int tok = gather ? ((rr < count) ? (list[rr] >> 1) : 0) : rr;
        aS[j] = (const char*)Xb + (size_t)tok * 4096 + SWZ(r, s);
    }
    int brr = tid >> 2, bss = tid & 3;
    size_t boff = (size_t)(n0 + brr) * 4096 + SWZ(brr, bss);
    const char* b1S = (const char*)W1 + boff;
    const char* b3S = (const char*)W3 + boff;

    f32x4 acc1[8][2], acc3[8][2];
#pragma unroll
    for (int i = 0; i < 8; ++i)
#pragma unroll
        for (int j = 0; j < 2; ++j) { acc1[i][j] = (f32x4)0.f; acc3[i][j] = (f32x4)0.f; }

#pragma unroll
    for (int p = 0; p < 3; ++p) {
        char* base = SMEM + p * 32768;
        int kb = p << 6;
        async_copy16(aS[0] + kb, base + tid * 16);
        async_copy16(aS[1] + kb, base + (512 + tid) * 16);
        async_copy16(b1S + kb, base + 16384 + tid * 16);
        async_copy16(b3S + kb, base + 24576 + tid * 16);
    }

    for (int t = 0; t < 64; ++t) {
        const char* base = SMEM + (t & 3) * 32768;
        int ts = (t + 3 < 64) ? (t + 3) : 63;
        char* sbase = SMEM + ((t + 3) & 3) * 32768;
        int skb = ts << 6;
        WAITVM(8);
        __builtin_amdgcn_s_barrier();
        // ---- phase 0: A+B1 frags, stage next A, MFMA acc1 ----
        bf16x8 af[8], bf[2];
#pragma unroll
        for (int mf = 0; mf < 8; ++mf) {
            int r = wm * 128 + mf * 16 + frow;
            af[mf] = *reinterpret_cast<const bf16x8*>(base + r * 64 + SWZ(r, fkg));
        }
#pragma unroll
        for (int nf = 0; nf < 2; ++nf) {
            int rb = wn * 32 + nf * 16 + frow;
            bf[nf] = *reinterpret_cast<const bf16x8*>(base + 16384 + rb * 64 + SWZ(rb, fkg));
        }
        async_copy16(aS[0] + skb, sbase + tid * 16);
        async_copy16(aS[1] + skb, sbase + (512 + tid) * 16);
        __builtin_amdgcn_s_setprio(1);
#pragma unroll
        for (int mf = 0; mf < 8; ++mf)
#pragma unroll
            for (int nf = 0; nf < 2; ++nf)
                acc1[mf][nf] = __builtin_amdgcn_mfma_f32_16x16x32_bf16(
                    af[mf], bf[nf], acc1[mf][nf], 0, 0, 0);
        __builtin_amdgcn_s_setprio(0);
        __builtin_amdgcn_s_barrier();
        // ---- phase 1: B3 frags, stage next B, MFMA acc3 ----
#pragma unroll
        for (int nf = 0; nf < 2; ++nf) {
            int rb = wn * 32 + nf * 16 + frow;
            bf[nf] = *reinterpret_cast<const bf16x8*>(base + 24576 + rb * 64 + SWZ(rb, fkg));
        }
        async_copy16(b1S + skb, sbase + 16384 + tid * 16);
        async_copy16(b3S + skb, sbase + 24576 + tid * 16);
        __builtin_amdgcn_s_setprio(1);
#pragma unroll
        for (int mf = 0; mf < 8; ++mf)
#pragma unroll
            for (int nf = 0; nf < 2; ++nf)
                acc3[mf][nf] = __builtin_amdgcn_mfma_f32_16x16x32_bf16(
                    af[mf], bf[nf], acc3[mf][nf], 0, 0, 0);
        __builtin_amdgcn_s_setprio(0);
    }
    WAITVM(0);

#pragma unroll
    for (int mf = 0; mf < 8; ++mf) {
#pragma unroll
        for (int jj = 0; jj < 4; ++jj) {
            int rl = wm * 128 + mf * 16 + fkg * 4 + jj;
            int rr = m0 + rl;
            int s;
            if (gather) { if (rr >= count) continue; s = list[rr]; }
            else s = rr;
            short* hp = H + (size_t)s * ldH + n0 + wn * 32 + frow;
#pragma unroll
            for (int nf = 0; nf < 2; ++nf)
                hp[nf * 16] = f2bf(silu1(acc1[mf][nf][jj]) * acc3[mf][nf][jj]);
        }
    }
}

// ---------------- out-GEMM: BM=256 BN=256 BK=32, 512 thr, 4-buf depth-3 ----------
// Per buf (32KB): A 256x64B (16K) | B 256x64B (16K). 8 waves 2m x 4n,
// wave-tile 128x64 (nf=4). Counted vmcnt(8).
__global__ __launch_bounds__(512) void moe_out_kernel(
    const short* __restrict__ Hs, const short* __restrict__ swt2, float* __restrict__ Y,
    const short* __restrict__ Hr, const short* __restrict__ rwt2, short* __restrict__ H2,
    const int* __restrict__ expert_list, const int* __restrict__ expert_count)
{
    __shared__ char SMEM[131072];
    int bid = blockIdx.x, tid = threadIdx.x;
    int xcd = bid & 7, qq = bid >> 3, mtile = qq & 7, gq = qq >> 3;
    int g = gq * 8 + xcd;
    if (g >= 72) return;
    bool gather;
    const short *A, *B;
    int ldKb, NIT, n0, count;
    const int* list = nullptr;
    int m0 = mtile * 256;
    if (g < 8) {
        gather = false; count = N_TOK;
        A = Hs; ldKb = FS_DIM * 2; NIT = 88; B = swt2; n0 = g * 256;
    } else {
        int g2 = g - 8, e = g2 >> 3;
        n0 = (g2 & 7) * 256;
        gather = true;
        count = expert_count[e];
        if (m0 >= count) return;
        list = expert_list + e * N_TOK;
        A = Hr; ldKb = F_DIM * 2; NIT = 44;
        B = rwt2 + (size_t)e * D_DIM * F_DIM;
    }

    int l = tid & 63, w = tid >> 6;
    int wm = w >> 2, wn = w & 3, frow = l & 15, fkg = l >> 4;

    const char* aS[2];
#pragma unroll
    for (int j = 0; j < 2; ++j) {
        int u = j * 512 + tid, r = u >> 2, s = u & 3;
        int rr = m0 + r;
        int arow = gather ? ((rr < count) ? list[rr] : 0) : rr;
        aS[j] = (const char*)A + (size_t)arow * ldKb + SWZ(r, s);
    }
    const char* bS[2];
#pragma unroll
    for (int j = 0; j < 2; ++j) {
        int u = j * 512 + tid, r = u >> 2, s = u & 3;
        bS[j] = (const char*)B + (size_t)(n0 + r) * ldKb + SWZ(r, s);
    }

    f32x4 acc[8][4];
#pragma unroll
    for (int i = 0; i < 8; ++i)
#pragma unroll
        for (int j = 0; j < 4; ++j) acc[i][j] = (f32x4)0.f;

#pragma unroll
    for (int p = 0; p < 3; ++p) {
        char* base = SMEM + p * 32768;
        int kb = p << 6;
        async_copy16(aS[0] + kb, base + tid * 16);
        async_copy16(aS[1] + kb, base + (512 + tid) * 16);
        async_copy16(bS[0] + kb, base + 16384 + tid * 16);
        async_copy16(bS[1] + kb, base + 16384 + (512 + tid) * 16);
    }

    for (int t = 0; t < NIT; ++t) {
        const char* base = SMEM + (t & 3) * 32768;
        int ts = (t + 3 < NIT) ? (t + 3) : (NIT - 1);
        char* sbase = SMEM + ((t + 3) & 3) * 32768;
        int skb = ts << 6;
        WAITVM(8);
        __builtin_amdgcn_s_barrier();
        // ---- phase 0: A frags + B frags 0,1; stage next A; 16 MFMA ----
        bf16x8 af[8], bf[4];
#pragma unroll
        for (int mf = 0; mf < 8; ++mf) {
            int r = wm * 128 + mf * 16 + frow;
            af[mf] = *reinterpret_cast<const bf16x8*>(base + r * 64 + SWZ(r, fkg));
        }
#pragma unroll
        for (int nf = 0; nf < 2; ++nf) {
            int rb = wn * 64 + nf * 16 + frow;
            bf[nf] = *reinterpret_cast<const bf16x8*>(base + 16384 + rb * 64 + SWZ(rb, fkg));
        }
        async_copy16(aS[0] + skb, sbase + tid * 16);
        async_copy16(aS[1] + skb, sbase + (512 + tid) * 16);
        __builtin_amdgcn_s_setprio(1);
#pragma unroll
        for (int mf = 0; mf < 8; ++mf)
#pragma unroll
            for (int nf = 0; nf < 2; ++nf)
                acc[mf][nf] = __builtin_amdgcn_mfma_f32_16x16x32_bf16(
                    af[mf], bf[nf], acc[mf][nf], 0, 0, 0);
        __builtin_amdgcn_s_setprio(0);
        __builtin_amdgcn_s_barrier();
        // ---- phase 1: B frags 2,3; stage next B; 16 MFMA ----
#pragma unroll
        for (int nf = 2; nf < 4; ++nf) {
            int rb = wn * 64 + nf * 16 + frow;
            bf[nf] = *reinterpret_cast<const bf16x8*>(base + 16384 + rb * 64 + SWZ(rb, fkg));
        }
        async_copy16(bS[0] + skb, sbase + 16384 + tid * 16);
        async_copy16(bS[1] + skb, sbase + 16384 + (512 + tid) * 16);
        __builtin_amdgcn_s_setprio(1);
#pragma unroll
        for (int mf = 0; mf < 8; ++mf)
#pragma unroll
            for (int nf = 2; nf < 4; ++nf)
                acc[mf][nf] = __builtin_amdgcn_mfma_f32_16x16x32_bf16(
                    af[mf], bf[nf], acc[mf][nf], 0, 0, 0);
        __builtin_amdgcn_s_setprio(0);
    }
    WAITVM(0);

#pragma unroll
    for (int mf = 0; mf < 8; ++mf) {
#pragma unroll
        for (int jj = 0; jj < 4; ++jj) {
            int rl = wm * 128 + mf * 16 + fkg * 4 + jj;
            int rr = m0 + rl;
            int s;
            if (gather) { if (rr >= count) continue; s = list[rr]; }
            else s = rr;
            int col = n0 + wn * 64 + frow;
            if (!gather) {
                float* op = Y + (size_t)s * D_DIM + col;
#pragma unroll
                for (int nf = 0; nf < 4; ++nf)
                    op[nf * 16] = acc[mf][nf][jj];
            } else {
                short* op = H2 + (size_t)s * D_DIM + col;
#pragma unroll
                for (int nf = 0; nf < 4; ++nf)
                    op[nf * 16] = f2bf(acc[mf][nf][jj]);
            }
        }
    }
}

// ---------------- combine (H2 bf16) ----------------
__global__ __launch_bounds__(256) void combine_kernel(
    float* __restrict__ Y, const short* __restrict__ H2,
    const float* __restrict__ assign_w)
{
    int tok = blockIdx.x, tid = threadIdx.x;
    float w0 = assign_w[2 * tok];
    float w1 = assign_w[2 * tok + 1];
    const short* h0 = H2 + (size_t)(2 * tok) * D_DIM + tid * 8;
    const short* h1 = h0 + D_DIM;
    bf16x8 a = *reinterpret_cast<const bf16x8*>(h0);
    bf16x8 b = *reinterpret_cast<const bf16x8*>(h1);
    float* y = Y + (size_t)tok * D_DIM + tid * 8;
    float4 y0 = *reinterpret_cast<float4*>(y);
    float4 y1 = *reinterpret_cast<float4*>(y + 4);
    y0.x = fmaf(w0, bf2f(a[0]), fmaf(w1, bf2f(b[0]), y0.x));
    y0.y = fmaf(w0, bf2f(a[1]), fmaf(w1, bf2f(b[1]), y0.y));
    y0.z = fmaf(w0, bf2f(a[2]), fmaf(w1, bf2f(b[2]), y0.z));
    y0.w = fmaf(w0, bf2f(a[3]), fmaf(w1, bf2f(b[3]), y0.w));
    y1.x = fmaf(w0, bf2f(a[4]), fmaf(w1, bf2f(b[4]), y1.x));
    y1.y = fmaf(w0, bf2f(a[5]), fmaf(w1, bf2f(b[5]), y1.y));
    y1.z = fmaf(w0, bf2f(a[6]), fmaf(w1, bf2f(b[6]), y1.z));
    y1.w = fmaf(w0, bf2f(a[7]), fmaf(w1, bf2f(b[7]), y1.w));
    *reinterpret_cast<float4*>(y) = y0;
    *reinterpret_cast<float4*>(y + 4) = y1;
}

extern "C" void kernel_launch(void* const* d_in, const int* in_sizes, int n_in,
                              void* d_out, int out_size, void* d_ws, size_t ws_size,
                              hipStream_t stream) {
    const float* x   = (const float*)d_in[0];
    const float* gw  = (const float*)d_in[1];
    const float* sw1 = (const float*)d_in[2];
    const float* sw2 = (const float*)d_in[3];
    const float* sw3 = (const float*)d_in[4];
    const float* rw1 = (const float*)d_in[5];
    const float* rw2 = (const float*)d_in[6];
    const float* rw3 = (const float*)d_in[7];
    float* Y = (float*)d_out;

    char* ws = (char*)d_ws;
    float* assign_w     = (float*)(ws);
    int*   expert_count = (int*)(ws + 16384);
    int*   expert_list  = (int*)(ws + 16384 + 256);

    const size_t XB_OFF   = 131072;
    const size_t SWT1_OFF = XB_OFF + 8388608ull;
    const size_t SWT3_OFF = SWT1_OFF + 11534336ull;
    const size_t SWT2_OFF = SWT3_OFF + 11534336ull;
    const size_t RWT1_OFF = SWT2_OFF + 11534336ull;
    const size_t RWT3_OFF = RWT1_OFF + 46137344ull;
    const size_t RWT2_OFF = RWT3_OFF + 46137344ull;
    const size_t HS_OFF   = RWT2_OFF + 46137344ull;
    const size_t HR_OFF   = HS_OFF + 11534336ull;
    const size_t H2_OFF   = HR_OFF + 11534336ull;

    short* Xb   = (short*)(ws + XB_OFF);
    short* swt1 = (short*)(ws + SWT1_OFF);
    short* swt3 = (short*)(ws + SWT3_OFF);
    short* swt2 = (short*)(ws + SWT2_OFF);
    short* rwt1 = (short*)(ws + RWT1_OFF);
    short* rwt3 = (short*)(ws + RWT3_OFF);
    short* rwt2 = (short*)(ws + RWT2_OFF);
    short* Hs   = (short*)(ws + HS_OFF);
    short* Hr   = (short*)(ws + HR_OFF);
    short* H2   = (short*)(ws + H2_OFF);

    hipMemsetAsync(expert_count, 0, E_NUM * sizeof(int), stream);

    prep_kernel<<<16640, 256, 0, stream>>>(
        x, gw, assign_w, expert_count, expert_list, Xb,
        sw1, swt1, sw3, swt3, rw1, rwt1, rw3, rwt3);

    // 110 groups (22 shared-in + 88 routed-in) x 8 mtiles -> 896 + 3520 transpose
    moe_in_kernel<<<4416, 512, 0, stream>>>(
        Xb, swt1, swt3, Hs, rwt1, rwt3, Hr,
        expert_list, expert_count, sw2, swt2, rw2, rwt2);

    // 72 groups (8 shared-out + 64 routed-out) x 8 mtiles -> 576
    moe_out_kernel<<<576, 512, 0, stream>>>(
        Hs, swt2, Y, Hr, rwt2, H2, expert_list, expert_count);

    combine_kernel<<<N_TOK, 256, 0, stream>>>(Y, H2, assign_w);
}

// Round 12
// 368.553 us; speedup vs baseline: 1.1178x; 1.0350x over previous
//
#include <hip/hip_runtime.h>
#include <hip/hip_bf16.h>
#include <math.h>

#define D_DIM 2048
#define F_DIM 1408
#define FS_DIM 2816
#define E_NUM 8
#define N_TOK 2048

typedef __attribute__((ext_vector_type(8))) short bf16x8;
typedef __attribute__((ext_vector_type(4))) float f32x4;

#define WAITVM(n) asm volatile("s_waitcnt vmcnt(" #n ")" ::: "memory")

__device__ inline short f2bf(float f) {
    __hip_bfloat16 h = __float2bfloat16(f);
    return *reinterpret_cast<short*>(&h);
}
__device__ inline float bf2f(short s) {
    __hip_bfloat16 h; *reinterpret_cast<short*>(&h) = s;
    return __bfloat162float(h);
}
__device__ inline float silu1(float v) { return v / (1.f + expf(-v)); }

__device__ inline void async_copy16(const void* g, void* l) {
    __builtin_amdgcn_global_load_lds(
        (const __attribute__((address_space(1))) void*)g,
        (__attribute__((address_space(3))) void*)l, 16, 0, 0);
}

// swizzle for 64B LDS rows: 16B slot s of row r stored at s ^ ((r>>1)&3)
#define SWZ(r, s) ((((s) ^ (((r) >> 1) & 3)) & 3) << 4)

// 64x64 transpose+convert tile, 256 threads
__device__ inline void t64h(const float* in, short* out, int K, int N,
                            int kt, int nt, float (*tile)[65], int t)
{
    int k0 = kt * 64, n0 = nt * 64;
    int tr = t >> 4, tc4 = (t & 15) * 4;
#pragma unroll
    for (int i = 0; i < 4; ++i) {
        int r = tr + i * 16;
        float4 v = *reinterpret_cast<const float4*>(in + (size_t)(k0 + r) * N + n0 + tc4);
        tile[r][tc4 + 0] = v.x; tile[r][tc4 + 1] = v.y;
        tile[r][tc4 + 2] = v.z; tile[r][tc4 + 3] = v.w;
    }
    __syncthreads();
#pragma unroll
    for (int i = 0; i < 4; ++i) {
        int n = tr + i * 16;
        short4 s4;
        s4.x = f2bf(tile[tc4 + 0][n]);
        s4.y = f2bf(tile[tc4 + 1][n]);
        s4.z = f2bf(tile[tc4 + 2][n]);
        s4.w = f2bf(tile[tc4 + 3][n]);
        *reinterpret_cast<short4*>(out + (size_t)(n0 + n) * K + k0 + tc4) = s4;
    }
}

// ---------------- prep: gate | cvt_x | transpose(sw1,sw3,rw1,rw3) ----------------
__global__ __launch_bounds__(256) void prep_kernel(
    const float* __restrict__ x, const float* __restrict__ gw,
    float* __restrict__ assign_w, int* __restrict__ expert_count,
    int* __restrict__ expert_list, short* __restrict__ Xb,
    const float* __restrict__ sw1, short* __restrict__ swt1,
    const float* __restrict__ sw3, short* __restrict__ swt3,
    const float* __restrict__ rw1, short* __restrict__ rwt1,
    const float* __restrict__ rw3, short* __restrict__ rwt3)
{
    __shared__ float tile[64][65];
    int bid = blockIdx.x;
    int tid = threadIdx.x;
    if (bid < 512) {
        int wid = bid * 4 + (tid >> 6);
        int lane = tid & 63;
        const float* xr = x + (size_t)wid * D_DIM;
        float p[E_NUM];
#pragma unroll
        for (int e = 0; e < E_NUM; ++e) p[e] = 0.f;
        for (int d = lane; d < D_DIM; d += 64) {
            float xv = xr[d];
            const float4* g = reinterpret_cast<const float4*>(gw + (size_t)d * E_NUM);
            float4 g0 = g[0], g1 = g[1];
            p[0] = fmaf(xv, g0.x, p[0]); p[1] = fmaf(xv, g0.y, p[1]);
            p[2] = fmaf(xv, g0.z, p[2]); p[3] = fmaf(xv, g0.w, p[3]);
            p[4] = fmaf(xv, g1.x, p[4]); p[5] = fmaf(xv, g1.y, p[5]);
            p[6] = fmaf(xv, g1.z, p[6]); p[7] = fmaf(xv, g1.w, p[7]);
        }
#pragma unroll
        for (int off = 32; off > 0; off >>= 1)
#pragma unroll
            for (int e = 0; e < E_NUM; ++e)
                p[e] += __shfl_xor(p[e], off, 64);
        if (lane == 0) {
            float m = p[0];
#pragma unroll
            for (int e = 1; e < E_NUM; ++e) m = fmaxf(m, p[e]);
            float s = 0.f, pr[E_NUM];
#pragma unroll
            for (int e = 0; e < E_NUM; ++e) { pr[e] = expf(p[e] - m); s += pr[e]; }
            float inv = 1.f / s;
#pragma unroll
            for (int e = 0; e < E_NUM; ++e) pr[e] *= inv;
            int i0 = 0;
#pragma unroll
            for (int e = 1; e < E_NUM; ++e) if (pr[e] > pr[i0]) i0 = e;
            int i1 = (i0 == 0) ? 1 : 0;
#pragma unroll
            for (int e = 0; e < E_NUM; ++e) if (e != i0 && pr[e] > pr[i1]) i1 = e;
            int s0 = wid * 2, s1 = wid * 2 + 1;
            assign_w[s0] = pr[i0];
            assign_w[s1] = pr[i1];
            int p0 = atomicAdd(&expert_count[i0], 1);
            expert_list[i0 * N_TOK + p0] = s0;
            int p1 = atomicAdd(&expert_count[i1], 1);
            expert_list[i1 * N_TOK + p1] = s1;
        }
    } else if (bid < 2560) {
        int i = ((bid - 512) * 256 + tid) * 8;
        float4 v0 = *reinterpret_cast<const float4*>(x + i);
        float4 v1 = *reinterpret_cast<const float4*>(x + i + 4);
        bf16x8 o;
        o[0] = f2bf(v0.x); o[1] = f2bf(v0.y); o[2] = f2bf(v0.z); o[3] = f2bf(v0.w);
        o[4] = f2bf(v1.x); o[5] = f2bf(v1.y); o[6] = f2bf(v1.z); o[7] = f2bf(v1.w);
        *reinterpret_cast<bf16x8*>(Xb + i) = o;
    } else if (bid < 3968) {
        int t = bid - 2560;
        t64h(sw1, swt1, D_DIM, FS_DIM, t % 32, t / 32, tile, tid);
    } else if (bid < 5376) {
        int t = bid - 3968;
        t64h(sw3, swt3, D_DIM, FS_DIM, t % 32, t / 32, tile, tid);
    } else if (bid < 11008) {
        int t = bid - 5376;
        int e = t / 704, r = t % 704;
        t64h(rw1 + (size_t)e * D_DIM * F_DIM, rwt1 + (size_t)e * F_DIM * D_DIM,
             D_DIM, F_DIM, r % 32, r / 32, tile, tid);
    } else {
        int t = bid - 11008;
        int e = t / 704, r = t % 704;
        t64h(rw3 + (size_t)e * D_DIM * F_DIM, rwt3 + (size_t)e * F_DIM * D_DIM,
             D_DIM, F_DIM, r % 32, r / 32, tile, tid);
    }
}

// ---------------- in-GEMM: BM=128, BN=64 per B, BK=32, 256 thr, 3-buf depth-2 ----
// Per buf (16KB): A 128x64B (8K) | B1 64x64B (4K) | B3 (4K). 4 waves 2m x 2n,
// wave-tile 64x32 per B. One barrier/iter; WAITVM(4) counted; 3 blocks/CU.
__global__ __launch_bounds__(256) void moe_in_kernel(
    const short* __restrict__ Xb,
    const short* __restrict__ swt1, const short* __restrict__ swt3, short* __restrict__ Hs,
    const short* __restrict__ rwt1, const short* __restrict__ rwt3, short* __restrict__ Hr,
    const int* __restrict__ expert_list, const int* __restrict__ expert_count,
    const float* __restrict__ sw2, short* __restrict__ swt2,
    const float* __restrict__ rw2, short* __restrict__ rwt2)
{
    __shared__ char SMEM[49152];
    int bid = blockIdx.x, tid = threadIdx.x;

    if (bid >= 3584) {
        // appended w2 transposes (1 tile per 256-thread block)
        int t2 = bid - 3584;
        float (*tile)[65] = reinterpret_cast<float (*)[65]>(SMEM);
        if (t2 < 1408) {
            t64h(sw2, swt2, FS_DIM, D_DIM, t2 % 44, t2 / 44, tile, tid);
        } else {
            int r = t2 - 1408;
            int e = r / 704, rr = r % 704;
            t64h(rw2 + (size_t)e * F_DIM * D_DIM, rwt2 + (size_t)e * D_DIM * F_DIM,
                 F_DIM, D_DIM, rr % 22, rr / 22, tile, tid);
        }
        return;
    }

    int xcd = bid & 7, qq = bid >> 3, mtile = qq & 15, gq = qq >> 4;
    int g = gq * 8 + xcd;
    if (g >= 220) return;
    bool gather;
    const short *W1, *W3;
    short* H;
    int ldH, n0, count;
    const int* list = nullptr;
    int m0 = mtile * 128;
    if (g < 44) {
        gather = false; count = N_TOK;
        W1 = swt1; W3 = swt3; H = Hs; ldH = FS_DIM; n0 = g * 64;
    } else {
        int g2 = g - 44, e = g2 / 22;
        n0 = (g2 % 22) * 64;
        gather = true;
        count = expert_count[e];
        if (m0 >= count) return;
        list = expert_list + e * N_TOK;
        W1 = rwt1 + (size_t)e * F_DIM * D_DIM;
        W3 = rwt3 + (size_t)e * F_DIM * D_DIM;
        H = Hr; ldH = F_DIM;
    }

    int l = tid & 63, w = tid >> 6;
    int wm = w >> 1, wn = w & 1, frow = l & 15, fkg = l >> 4;

    // staging sources (pre-swizzled)
    const char* aS[2];
#pragma unroll
    for (int j = 0; j < 2; ++j) {
        int u = j * 256 + tid, r = u >> 2, s = u & 3;
        int rr = m0 + r;
        int tok = gather ? ((rr < count) ? (list[rr] >> 1) : 0) : rr;
        aS[j] = (const char*)Xb + (size_t)tok * 4096 + SWZ(r, s);
    }
    int brr = tid >> 2, bss = tid & 3;
    size_t boff = (size_t)(n0 + brr) * 4096 + SWZ(brr, bss);
    const char* b1S = (const char*)W1 + boff;
    const char* b3S = (const char*)W3 + boff;

    f32x4 acc1[4][2], acc3[4][2];
#pragma unroll
    for (int i = 0; i < 4; ++i)
#pragma unroll
        for (int j = 0; j < 2; ++j) { acc1[i][j] = (f32x4)0.f; acc3[i][j] = (f32x4)0.f; }

    // prologue: stage tiles 0,1 (4 loads each per thread)
#pragma unroll
    for (int p = 0; p < 2; ++p) {
        char* base = SMEM + p * 16384;
        int kb = p << 6;
        async_copy16(aS[0] + kb, base + tid * 16);
        async_copy16(aS[1] + kb, base + (256 + tid) * 16);
        async_copy16(b1S + kb, base + 8192 + tid * 16);
        async_copy16(b3S + kb, base + 12288 + tid * 16);
    }

    const int NIT = 64;
    for (int t = 0; t < NIT; ++t) {
        const char* base = SMEM + (t % 3) * 16384;
        WAITVM(4);                       // own tile-t loads complete (t+1 in flight)
        __builtin_amdgcn_s_barrier();    // all waves' tile-t loads complete
        {   // stage tile t+2 (into buf consumed at iter t-1)
            int ts = (t + 2 < NIT) ? (t + 2) : (NIT - 1);
            char* sbase = SMEM + ((t + 2) % 3) * 16384;
            int skb = ts << 6;
            async_copy16(aS[0] + skb, sbase + tid * 16);
            async_copy16(aS[1] + skb, sbase + (256 + tid) * 16);
            async_copy16(b1S + skb, sbase + 8192 + tid * 16);
            async_copy16(b3S + skb, sbase + 12288 + tid * 16);
        }
        bf16x8 af[4], b1f[2], b3f[2];
#pragma unroll
        for (int mf = 0; mf < 4; ++mf) {
            int r = wm * 64 + mf * 16 + frow;
            af[mf] = *reinterpret_cast<const bf16x8*>(base + r * 64 + SWZ(r, fkg));
        }
#pragma unroll
        for (int nf = 0; nf < 2; ++nf) {
            int rb = wn * 32 + nf * 16 + frow;
            b1f[nf] = *reinterpret_cast<const bf16x8*>(base + 8192 + rb * 64 + SWZ(rb, fkg));
            b3f[nf] = *reinterpret_cast<const bf16x8*>(base + 12288 + rb * 64 + SWZ(rb, fkg));
        }
        __builtin_amdgcn_s_setprio(1);
#pragma unroll
        for (int mf = 0; mf < 4; ++mf)
#pragma unroll
            for (int nf = 0; nf < 2; ++nf) {
                acc1[mf][nf] = __builtin_amdgcn_mfma_f32_16x16x32_bf16(
                    af[mf], b1f[nf], acc1[mf][nf], 0, 0, 0);
                acc3[mf][nf] = __builtin_amdgcn_mfma_f32_16x16x32_bf16(
                    af[mf], b3f[nf], acc3[mf][nf], 0, 0, 0);
            }
        __builtin_amdgcn_s_setprio(0);
    }
    WAITVM(0);

#pragma unroll
    for (int mf = 0; mf < 4; ++mf) {
#pragma unroll
        for (int jj = 0; jj < 4; ++jj) {
            int rl = wm * 64 + mf * 16 + fkg * 4 + jj;
            int rr = m0 + rl;
            int s;
            if (gather) { if (rr >= count) continue; s = list[rr]; }
            else s = rr;
            short* hp = H + (size_t)s * ldH + n0 + wn * 32 + frow;
#pragma unroll
            for (int nf = 0; nf < 2; ++nf)
                hp[nf * 16] = f2bf(silu1(acc1[mf][nf][jj]) * acc3[mf][nf][jj]);
        }
    }
}

// ---------------- out-GEMM: BM=128 BN=128 BK=32, 256 thr, 3-buf depth-2 ----------
// Per buf (16KB): A 128x64B (8K) | B 128x64B (8K). 4 waves 2m x 2n,
// wave-tile 64x64 (nf=4). WAITVM(4); one barrier/iter.
__global__ __launch_bounds__(256) void moe_out_kernel(
    const short* __restrict__ Hs, const short* __restrict__ swt2, float* __restrict__ Y,
    const short* __restrict__ Hr, const short* __restrict__ rwt2, short* __restrict__ H2,
    const int* __restrict__ expert_list, const int* __restrict__ expert_count)
{
    __shared__ char SMEM[49152];
    int bid = blockIdx.x, tid = threadIdx.x;
    int xcd = bid & 7, qq = bid >> 3, mtile = qq & 15, gq = qq >> 4;
    int g = gq * 8 + xcd;
    if (g >= 144) return;
    bool gather;
    const short *A, *B;
    int ldKb, NIT, n0, count;
    const int* list = nullptr;
    int m0 = mtile * 128;
    if (g < 16) {
        gather = false; count = N_TOK;
        A = Hs; ldKb = FS_DIM * 2; NIT = 88; B = swt2; n0 = g * 128;
    } else {
        int g2 = g - 16, e = g2 >> 4;
        n0 = (g2 & 15) * 128;
        gather = true;
        count = expert_count[e];
        if (m0 >= count) return;
        list = expert_list + e * N_TOK;
        A = Hr; ldKb = F_DIM * 2; NIT = 44;
        B = rwt2 + (size_t)e * D_DIM * F_DIM;
    }

    int l = tid & 63, w = tid >> 6;
    int wm = w >> 1, wn = w & 1, frow = l & 15, fkg = l >> 4;

    const char* aS[2];
#pragma unroll
    for (int j = 0; j < 2; ++j) {
        int u = j * 256 + tid, r = u >> 2, s = u & 3;
        int rr = m0 + r;
        int arow = gather ? ((rr < count) ? list[rr] : 0) : rr;
        aS[j] = (const char*)A + (size_t)arow * ldKb + SWZ(r, s);
    }
    const char* bS[2];
#pragma unroll
    for (int j = 0; j < 2; ++j) {
        int u = j * 256 + tid, r = u >> 2, s = u & 3;
        bS[j] = (const char*)B + (size_t)(n0 + r) * ldKb + SWZ(r, s);
    }

    f32x4 acc[4][4];
#pragma unroll
    for (int i = 0; i < 4; ++i)
#pragma unroll
        for (int j = 0; j < 4; ++j) acc[i][j] = (f32x4)0.f;

#pragma unroll
    for (int p = 0; p < 2; ++p) {
        char* base = SMEM + p * 16384;
        int kb = p << 6;
        async_copy16(aS[0] + kb, base + tid * 16);
        async_copy16(aS[1] + kb, base + (256 + tid) * 16);
        async_copy16(bS[0] + kb, base + 8192 + tid * 16);
        async_copy16(bS[1] + kb, base + 8192 + (256 + tid) * 16);
    }

    for (int t = 0; t < NIT; ++t) {
        const char* base = SMEM + (t % 3) * 16384;
        WAITVM(4);
        __builtin_amdgcn_s_barrier();
        {
            int ts = (t + 2 < NIT) ? (t + 2) : (NIT - 1);
            char* sbase = SMEM + ((t + 2) % 3) * 16384;
            int skb = ts << 6;
            async_copy16(aS[0] + skb, sbase + tid * 16);
            async_copy16(aS[1] + skb, sbase + (256 + tid) * 16);
            async_copy16(bS[0] + skb, sbase + 8192 + tid * 16);
            async_copy16(bS[1] + skb, sbase + 8192 + (256 + tid) * 16);
        }
        bf16x8 af[4], bf[4];
#pragma unroll
        for (int mf = 0; mf < 4; ++mf) {
            int r = wm * 64 + mf * 16 + frow;
            af[mf] = *reinterpret_cast<const bf16x8*>(base + r * 64 + SWZ(r, fkg));
        }
#pragma unroll
        for (int nf = 0; nf < 4; ++nf) {
            int rb = wn * 64 + nf * 16 + frow;
            bf[nf] = *reinterpret_cast<const bf16x8*>(base + 8192 + rb * 64 + SWZ(rb, fkg));
        }
        __builtin_amdgcn_s_setprio(1);
#pragma unroll
        for (int mf = 0; mf < 4; ++mf)
#pragma unroll
            for (int nf = 0; nf < 4; ++nf)
                acc[mf][nf] = __builtin_amdgcn_mfma_f32_16x16x32_bf16(
                    af[mf], bf[nf], acc[mf][nf], 0, 0, 0);
        __builtin_amdgcn_s_setprio(0);
    }
    WAITVM(0);

#pragma unroll
    for (int mf = 0; mf < 4; ++mf) {
#pragma unroll
        for (int jj = 0; jj < 4; ++jj) {
            int rl = wm * 64 + mf * 16 + fkg * 4 + jj;
            int rr = m0 + rl;
            int s;
            if (gather) { if (rr >= count) continue; s = list[rr]; }
            else s = rr;
            int col = n0 + wn * 64 + frow;
            if (!gather) {
                float* op = Y + (size_t)s * D_DIM + col;
#pragma unroll
                for (int nf = 0; nf < 4; ++nf)
                    op[nf * 16] = acc[mf][nf][jj];
            } else {
                short* op = H2 + (size_t)s * D_DIM + col;
#pragma unroll
                for (int nf = 0; nf < 4; ++nf)
                    op[nf * 16] = f2bf(acc[mf][nf][jj]);
            }
        }
    }
}

// ---------------- combine (H2 bf16) ----------------
__global__ __launch_bounds__(256) void combine_kernel(
    float* __restrict__ Y, const short* __restrict__ H2,
    const float* __restrict__ assign_w)
{
    int tok = blockIdx.x, tid = threadIdx.x;
    float w0 = assign_w[2 * tok];
    float w1 = assign_w[2 * tok + 1];
    const short* h0 = H2 + (size_t)(2 * tok) * D_DIM + tid * 8;
    const short* h1 = h0 + D_DIM;
    bf16x8 a = *reinterpret_cast<const bf16x8*>(h0);
    bf16x8 b = *reinterpret_cast<const bf16x8*>(h1);
    float* y = Y + (size_t)tok * D_DIM + tid * 8;
    float4 y0 = *reinterpret_cast<float4*>(y);
    float4 y1 = *reinterpret_cast<float4*>(y + 4);
    y0.x = fmaf(w0, bf2f(a[0]), fmaf(w1, bf2f(b[0]), y0.x));
    y0.y = fmaf(w0, bf2f(a[1]), fmaf(w1, bf2f(b[1]), y0.y));
    y0.z = fmaf(w0, bf2f(a[2]), fmaf(w1, bf2f(b[2]), y0.z));
    y0.w = fmaf(w0, bf2f(a[3]), fmaf(w1, bf2f(b[3]), y0.w));
    y1.x = fmaf(w0, bf2f(a[4]), fmaf(w1, bf2f(b[4]), y1.x));
    y1.y = fmaf(w0, bf2f(a[5]), fmaf(w1, bf2f(b[5]), y1.y));
    y1.z = fmaf(w0, bf2f(a[6]), fmaf(w1, bf2f(b[6]), y1.z));
    y1.w = fmaf(w0, bf2f(a[7]), fmaf(w1, bf2f(b[7]), y1.w));
    *reinterpret_cast<float4*>(y) = y0;
    *reinterpret_cast<float4*>(y + 4) = y1;
}

extern "C" void kernel_launch(void* const* d_in, const int* in_sizes, int n_in,
                              void* d_out, int out_size, void* d_ws, size_t ws_size,
                              hipStream_t stream) {
    const float* x   = (const float*)d_in[0];
    const float* gw  = (const float*)d_in[1];
    const float* sw1 = (const float*)d_in[2];
    const float* sw2 = (const float*)d_in[3];
    const float* sw3 = (const float*)d_in[4];
    const float* rw1 = (const float*)d_in[5];
    const float* rw2 = (const float*)d_in[6];
    const float* rw3 = (const float*)d_in[7];
    float* Y = (float*)d_out;

    char* ws = (char*)d_ws;
    float* assign_w     = (float*)(ws);
    int*   expert_count = (int*)(ws + 16384);
    int*   expert_list  = (int*)(ws + 16384 + 256);

    const size_t XB_OFF   = 131072;
    const size_t SWT1_OFF = XB_OFF + 8388608ull;
    const size_t SWT3_OFF = SWT1_OFF + 11534336ull;
    const size_t SWT2_OFF = SWT3_OFF + 11534336ull;
    const size_t RWT1_OFF = SWT2_OFF + 11534336ull;
    const size_t RWT3_OFF = RWT1_OFF + 46137344ull;
    const size_t RWT2_OFF = RWT3_OFF + 46137344ull;
    const size_t HS_OFF   = RWT2_OFF + 46137344ull;
    const size_t HR_OFF   = HS_OFF + 11534336ull;
    const size_t H2_OFF   = HR_OFF + 11534336ull;

    short* Xb   = (short*)(ws + XB_OFF);
    short* swt1 = (short*)(ws + SWT1_OFF);
    short* swt3 = (short*)(ws + SWT3_OFF);
    short* swt2 = (short*)(ws + SWT2_OFF);
    short* rwt1 = (short*)(ws + RWT1_OFF);
    short* rwt3 = (short*)(ws + RWT3_OFF);
    short* rwt2 = (short*)(ws + RWT2_OFF);
    short* Hs   = (short*)(ws + HS_OFF);
    short* Hr   = (short*)(ws + HR_OFF);
    short* H2   = (short*)(ws + H2_OFF);

    hipMemsetAsync(expert_count, 0, E_NUM * sizeof(int), stream);

    prep_kernel<<<16640, 256, 0, stream>>>(
        x, gw, assign_w, expert_count, expert_list, Xb,
        sw1, swt1, sw3, swt3, rw1, rwt1, rw3, rwt3);

    // 220 groups (44 shared-in + 176 routed-in) x 16 mtiles, XCD-mapped -> 3584
    // + 7040 transpose blocks
    moe_in_kernel<<<10624, 256, 0, stream>>>(
        Xb, swt1, swt3, Hs, rwt1, rwt3, Hr,
        expert_list, expert_count, sw2, swt2, rw2, rwt2);

    // 144 groups (16 shared-out + 128 routed-out) x 16 mtiles -> 2304
    moe_out_kernel<<<2304, 256, 0, stream>>>(
        Hs, swt2, Y, Hr, rwt2, H2, expert_list, expert_count);

    combine_kernel<<<N_TOK, 256, 0, stream>>>(Y, H2, assign_w);
}